// Round 8
// baseline (221.280 us; speedup 1.0000x reference)
//
#include <hip/hip_runtime.h>
#include <hip/hip_bf16.h>

// Problem constants (L=1024, B=4, E=1024, H=16, D=64)
#define SL 1024
#define BB 4
#define EE 1024
#define HH 16
#define DD 64
#define BHC 64          // BB*HH
#define M1 4096         // SL*BB

typedef __bf16 bf16x8 __attribute__((ext_vector_type(8)));
typedef __bf16 bf16x4 __attribute__((ext_vector_type(4)));
typedef float f32x4 __attribute__((ext_vector_type(4)));

typedef __attribute__((address_space(3))) unsigned int lds_u32;
typedef const __attribute__((address_space(1))) unsigned int g_u32;

__device__ __forceinline__ f32x4 mfma16(bf16x8 a, bf16x8 b, f32x4 c) {
    return __builtin_amdgcn_mfma_f32_16x16x32_bf16(a, b, c, 0, 0, 0);
}

// swizzled frag read: tile stored as 16B chunks with ch' = ch ^ (row&7)
#define FR(buf, row, chunk) (*(const bf16x8*)&(buf)[(row) * 64 + (((chunk) ^ ((row) & 7))) * 8])

// ---------------- fused prep: all f32->bf16 conversions + er flip ----------
// blocks [0,4096): query; [4096,7168): w_in; [7168,8192): w_out;
// [8192,8256): erf[r][d] = relpos[1023-r][d]. All segments exact multiples.
__global__ __launch_bounds__(256) void prep_k(const float* __restrict__ query,
                                              const float* __restrict__ w_in,
                                              const float* __restrict__ w_out,
                                              const float* __restrict__ rel,
                                              __bf16* __restrict__ qA,
                                              __bf16* __restrict__ winb,
                                              __bf16* __restrict__ woutb,
                                              __bf16* __restrict__ erfp) {
    int bid = blockIdx.x, tid = threadIdx.x;
    const float* src;
    __bf16* dst;
    int idx;
    if (bid < 4096)      { src = query; dst = qA;    idx = (bid * 256 + tid) * 4; }
    else if (bid < 7168) { src = w_in;  dst = winb;  idx = ((bid - 4096) * 256 + tid) * 4; }
    else if (bid < 8192) { src = w_out; dst = woutb; idx = ((bid - 7168) * 256 + tid) * 4; }
    else {
        int e4 = ((bid - 8192) * 256 + tid) * 4;
        int r = e4 >> 6, d = e4 & 63;
        float4 v = *(const float4*)&rel[(1023 - r) * 64 + d];
        bf16x4 o;
        o[0] = (__bf16)v.x; o[1] = (__bf16)v.y; o[2] = (__bf16)v.z; o[3] = (__bf16)v.w;
        *(bf16x4*)&erfp[e4] = o;
        return;
    }
    float4 v = *(const float4*)&src[idx];
    bf16x4 o;
    o[0] = (__bf16)v.x; o[1] = (__bf16)v.y; o[2] = (__bf16)v.z; o[3] = (__bf16)v.w;
    *(bf16x4*)&dst[idx] = o;
}

// ---------------- GEMM: C = A(MxK) @ B(NxK)^T + bias ----------------
// global_load_lds staging (m97 pattern). mode 0: repack epilogue -> q/k in
// [bh][l][d] (16B stores) and v DIRECTLY transposed into vT [bh][d][m]
// (8B stores). mode 1: fp32 store.
#define BMt 128
#define BNt 128
#define BKt 32
__global__ __launch_bounds__(256) void gemm_bt(const __bf16* __restrict__ A,
                                               const __bf16* __restrict__ Bm,
                                               const float* __restrict__ bias,
                                               int M, int N, int K, int mode,
                                               __bf16* __restrict__ q_ws,
                                               __bf16* __restrict__ k_ws,
                                               __bf16* __restrict__ vT_ws,
                                               float* __restrict__ outf) {
    __shared__ __bf16 As[BMt * BKt];
    __shared__ __bf16 Bs[BNt * BKt];
    int tid = threadIdx.x;
    int wave = tid >> 6, lane = tid & 63;
    int quad = lane >> 4, c = lane & 15;
    int ntiles = N / BNt;
    int bx = blockIdx.x % ntiles, by = blockIdx.x / ntiles;
    int m0 = by * BMt, n0 = bx * BNt;
    int wm = (wave >> 1) * 64, wn = (wave & 1) * 64;
    int srow = lane >> 2, scol = (lane & 3) * 8;   // staging: lane -> row/col8

    f32x4 acc[4][4] = {};
    for (int k0 = 0; k0 < K; k0 += BKt) {
        __syncthreads();
#pragma unroll
        for (int n = 0; n < 2; ++n) {
            int r0 = 32 * wave + 16 * n;
            const __bf16* ga = &A[(long)(m0 + r0 + srow) * K + k0 + scol];
            const __bf16* gb = &Bm[(long)(n0 + r0 + srow) * K + k0 + scol];
            __builtin_amdgcn_global_load_lds((g_u32*)ga, (lds_u32*)&As[r0 * BKt], 16, 0, 0);
            __builtin_amdgcn_global_load_lds((g_u32*)gb, (lds_u32*)&Bs[r0 * BKt], 16, 0, 0);
        }
        __syncthreads();
        bf16x8 af[4], bfr[4];
#pragma unroll
        for (int t = 0; t < 4; ++t) {
            af[t]  = *(const bf16x8*)&As[(wm + t * 16 + c) * BKt + quad * 8];
            bfr[t] = *(const bf16x8*)&Bs[(wn + t * 16 + c) * BKt + quad * 8];
        }
#pragma unroll
        for (int mt = 0; mt < 4; ++mt)
#pragma unroll
            for (int nt = 0; nt < 4; ++nt)
                acc[mt][nt] = mfma16(af[mt], bfr[nt], acc[mt][nt]);
    }

    if (mode == 1) {
#pragma unroll
        for (int mt = 0; mt < 4; ++mt)
#pragma unroll
            for (int nt = 0; nt < 4; ++nt) {
                int nn = n0 + wn + nt * 16 + c;
                float bv = bias[nn];
#pragma unroll
                for (int i = 0; i < 4; ++i) {
                    int mm = m0 + wm + mt * 16 + quad * 4 + i;
                    outf[(long)mm * N + nn] = acc[mt][nt][i] + bv;
                }
            }
        return;
    }
    // mode 0: LDS repack epilogue. Per-wave slab 16 x 72 in As/Bs (after sync).
    __syncthreads();
    __bf16* slab = ((wave < 2) ? As : Bs) + (wave & 1) * 2048;
    int nnb = n0 + wn;                 // wave's 64-col block: d = 16*nt + c
    int which = nnb >> 10;             // 0=q 1=k 2=v (uniform per wave)
    int hh = (nnb & 1023) >> 6;        // head (uniform per wave)
    float scale = (which == 0) ? 0.125f : 1.0f;
#pragma unroll
    for (int mt = 0; mt < 4; ++mt) {
#pragma unroll
        for (int nt = 0; nt < 4; ++nt) {
            float bv = bias[nnb + nt * 16 + c];
#pragma unroll
            for (int i = 0; i < 4; ++i)
                slab[(quad * 4 + i) * 72 + nt * 16 + c] =
                    (__bf16)((acc[mt][nt][i] + bv) * scale);
        }
        // intra-wave write->read: ordered via lgkmcnt, no barrier needed
        if (which < 2) {
            int mm = m0 + wm + mt * 16 + c;        // lane owns row c of the tile
            int l = mm >> 2, bb = mm & 3;
            __bf16* dstp = ((which == 0) ? q_ws : k_ws) +
                           ((long)(bb * 16 + hh) * 1024 + l) * 64;
            bf16x8 t0 = *(const bf16x8*)&slab[c * 72 + quad * 8];
            bf16x8 t1 = *(const bf16x8*)&slab[c * 72 + 32 + quad * 8];
            *(bf16x8*)&dstp[quad * 8] = t0;
            *(bf16x8*)&dstp[32 + quad * 8] = t1;
        } else {
            int d = quad * 16 + c;                 // lane owns one d column
            __bf16 tmp[16];
#pragma unroll
            for (int jr = 0; jr < 16; ++jr) tmp[jr] = slab[jr * 72 + d];
            int L0 = (m0 + wm + mt * 16) >> 2;     // 4 consecutive l per b
#pragma unroll
            for (int bs = 0; bs < 4; ++bs) {
                bf16x4 pk;
                pk[0] = tmp[bs]; pk[1] = tmp[4 + bs];
                pk[2] = tmp[8 + bs]; pk[3] = tmp[12 + bs];
                *(bf16x4*)&vT_ws[((long)(bs * 16 + hh) * 64 + d) * 1024 + L0] = pk;
            }
        }
    }
}

// ---------------- attention: single barrier per round -----------------------
// grid 512 (64 bh x 8 tiles of 128 l-rows, XCD swizzle), block 256 = 4 waves,
// wave owns 32 rows (two 16-row groups sharing K/V/E A-frags). K AND V are
// dist-1 double-buffered via global_load_lds (issued at round start for round
// kt-1, drained by the single end-of-round barrier -> full-round latency
// cover). erf B-frags are read DIRECTLY from global into regs at round start
// (erf is 128 KB, L2-resident; VGPR headroom 256 so no load sinking as in r5).
// Rel ring: 2 slots/wave; P reuses the dead slot. No softmax max-subtraction.
// LDS 69.6 KB -> 2 blocks/CU, all 512 blocks resident.
#define RSTn 72
#define RSLOT (32 * RSTn)
__global__ __launch_bounds__(256, 2) void attn_kernel(const __bf16* __restrict__ q_ws,
                                                      const __bf16* __restrict__ k_ws,
                                                      const __bf16* __restrict__ vT_ws,
                                                      const __bf16* __restrict__ erf,
                                                      __bf16* __restrict__ O_flat) {
    __shared__ __bf16 Ks[2][4096];            // 16 KB  K tiles (dist-1)
    __shared__ __bf16 Vs[2][4096];            // 16 KB  V^T tiles (dist-1)
    __shared__ __bf16 Ring[4][2][RSLOT];      // 36.9 KB rel ring + P (dead slot)

    int tid = threadIdx.x;
    int w = tid >> 6, lane = tid & 63;
    int q = lane >> 4, c = lane & 15;
    int bid = blockIdx.x;
    int x = bid & 7, ii = bid >> 3;           // XCD-localized swizzle
    int bh = x * 8 + (ii >> 3);
    int blk_l0 = (ii & 7) * 128;
    int b = bh >> 4, h = bh & 15;
    int l0w = blk_l0 + w * 32;

    __bf16* RW = &Ring[w][0][0];

    const __bf16* qp = q_ws + ((long)bh * 1024 + l0w) * 64;
    bf16x8 qf0[2], qf1[2];
    qf0[0] = *(const bf16x8*)&qp[c * 64 + q * 8];
    qf1[0] = *(const bf16x8*)&qp[c * 64 + 32 + q * 8];
    qf0[1] = *(const bf16x8*)&qp[(16 + c) * 64 + q * 8];
    qf1[1] = *(const bf16x8*)&qp[(16 + c) * 64 + 32 + q * 8];

    const __bf16* kbase = k_ws + (long)bh * 65536;
    const __bf16* vbase = vT_ws + (long)bh * 65536;

    // staging geometry: wave w covers chunk slots [128w, 128w+128)
    int sr[2], sc[2], ldo[2];
#pragma unroll
    for (int n = 0; n < 2; ++n) {
        int sidx = w * 128 + n * 64 + lane;
        sr[n] = sidx >> 3;
        sc[n] = (sidx & 7) ^ (sr[n] & 7);
        ldo[n] = (w * 128 + n * 64) * 8;
    }

    // prologue: K/V tile 15 -> parity 1
#pragma unroll
    for (int n = 0; n < 2; ++n) {
        __builtin_amdgcn_global_load_lds((g_u32*)(kbase + 15 * 4096 + sr[n] * 64 + sc[n] * 8),
                                         (lds_u32*)&Ks[1][ldo[n]], 16, 0, 0);
        __builtin_amdgcn_global_load_lds((g_u32*)(vbase + sr[n] * 1024 + 15 * 64 + sc[n] * 8),
                                         (lds_u32*)&Vs[1][ldo[n]], 16, 0, 0);
    }
    __syncthreads();

    f32x4 O[2][4] = {};
    float l_run[2] = {0.f, 0.f};

    for (int kt = 15; kt >= 0; --kt) {
        int p = kt & 1;
        // ---- issue next round's K/V DMA (drained at end-of-round barrier) ----
        if (kt > 0) {
#pragma unroll
            for (int n = 0; n < 2; ++n) {
                __builtin_amdgcn_global_load_lds(
                    (g_u32*)(kbase + (kt - 1) * 4096 + sr[n] * 64 + sc[n] * 8),
                    (lds_u32*)&Ks[p ^ 1][ldo[n]], 16, 0, 0);
                __builtin_amdgcn_global_load_lds(
                    (g_u32*)(vbase + sr[n] * 1024 + (kt - 1) * 64 + sc[n] * 8),
                    (lds_u32*)&Vs[p ^ 1][ldo[n]], 16, 0, 0);
            }
        }
        // ---- issue erf B-frag register loads early (covered by S phase) ----
        int rmax = l0w + 31 - kt * 64;
        int t1 = rmax >> 6;
        bf16x8 ea0[4], ea1[4];
        if (rmax >= 0) {
            const __bf16* ep = erf + (long)t1 * 4096;
#pragma unroll
            for (int s = 0; s < 4; ++s) {
                ea0[s] = *(const bf16x8*)&ep[(16 * s + c) * 64 + q * 8];
                ea1[s] = *(const bf16x8*)&ep[(16 * s + c) * 64 + 32 + q * 8];
            }
        }
        // ---- S^T = K Q^T (frags read once, both groups) ----
        const __bf16* Kp = Ks[p];
        bf16x8 ka0[4], ka1[4];
#pragma unroll
        for (int s = 0; s < 4; ++s) {
            int row = 16 * s + c;
            ka0[s] = FR(Kp, row, q);
            ka1[s] = FR(Kp, row, 4 + q);
        }
        f32x4 S[2][4];
#pragma unroll
        for (int g = 0; g < 2; ++g)
#pragma unroll
            for (int s = 0; s < 4; ++s) {
                f32x4 acc = {0.f, 0.f, 0.f, 0.f};
                acc = mfma16(ka0[s], qf0[g], acc);
                acc = mfma16(ka1[s], qf1[g], acc);
                S[g][s] = acc;
            }
        // ---- R phase: wave's new rel tile t1 (wave-local, no barrier) ----
        if (rmax >= 0) {
            __bf16* rt = RW + (t1 & 1) * RSLOT;
#pragma unroll
            for (int g = 0; g < 2; ++g)
#pragma unroll
                for (int s = 0; s < 4; ++s) {
                    f32x4 ar = {0.f, 0.f, 0.f, 0.f};
                    ar = mfma16(ea0[s], qf0[g], ar);
                    ar = mfma16(ea1[s], qf1[g], ar);
                    bf16x4 pk;
#pragma unroll
                    for (int i = 0; i < 4; ++i) pk[i] = (__bf16)ar[i];
                    *(bf16x4*)&rt[(g * 16 + c) * RSTn + 16 * s + 4 * q] = pk;
                }
            // gather: r = l - m; resident tiles {t1-1, t1} at slot (r>>6)&1
#pragma unroll
            for (int g = 0; g < 2; ++g) {
                int rb = l0w + g * 16 + c - kt * 64 - 4 * q;
#pragma unroll
                for (int s = 0; s < 4; ++s)
#pragma unroll
                    for (int i = 0; i < 4; ++i) {
                        int r = rb - 16 * s - i;
                        if (r >= 0)
                            S[g][s][i] += (float)RW[((r >> 6) & 1) * RSLOT +
                                                    (g * 16 + c) * RSTn + (r & 63)];
                    }
            }
        }
        int pslot = (rmax >= 0) ? ((t1 & 1) ^ 1) : 1;
        // ---- exp (no max) + lane-local sums ----
#pragma unroll
        for (int g = 0; g < 2; ++g) {
            float ps[4];
#pragma unroll
            for (int s = 0; s < 4; ++s) {
                float a = __expf(S[g][s][0]), b2 = __expf(S[g][s][1]);
                float c2 = __expf(S[g][s][2]), d2 = __expf(S[g][s][3]);
                S[g][s][0] = a; S[g][s][1] = b2; S[g][s][2] = c2; S[g][s][3] = d2;
                ps[s] = (a + b2) + (c2 + d2);
            }
            l_run[g] += (ps[0] + ps[1]) + (ps[2] + ps[3]);
        }
        // ---- P into ring's dead slot (b64 packed) ----
        __bf16* PW = RW + pslot * RSLOT;
#pragma unroll
        for (int g = 0; g < 2; ++g)
#pragma unroll
            for (int s = 0; s < 4; ++s) {
                bf16x4 pk;
#pragma unroll
                for (int i = 0; i < 4; ++i) pk[i] = (__bf16)S[g][s][i];
                *(bf16x4*)&PW[(g * 16 + c) * RSTn + 16 * s + 4 * q] = pk;
            }
        // ---- O^T += V^T P^T ----
        const __bf16* Vp = Vs[p];
        bf16x8 va0[4], va1[4];
#pragma unroll
        for (int s = 0; s < 4; ++s) {
            int row = 16 * s + c;
            va0[s] = FR(Vp, row, q);
            va1[s] = FR(Vp, row, 4 + q);
        }
        bf16x8 pa0[2], pa1[2];
#pragma unroll
        for (int g = 0; g < 2; ++g) {
            pa0[g] = *(const bf16x8*)&PW[(g * 16 + c) * RSTn + q * 8];
            pa1[g] = *(const bf16x8*)&PW[(g * 16 + c) * RSTn + 32 + q * 8];
        }
#pragma unroll
        for (int g = 0; g < 2; ++g)
#pragma unroll
            for (int s = 0; s < 4; ++s) {
                O[g][s] = mfma16(va0[s], pa0[g], O[g][s]);
                O[g][s] = mfma16(va1[s], pa1[g], O[g][s]);
            }
        __syncthreads();   // SINGLE barrier: drains next-round DMA, guards parity swap
    }
    // ---- epilogue ----
#pragma unroll
    for (int g = 0; g < 2; ++g) {
        float tot = l_run[g];
        tot += __shfl_xor(tot, 16);
        tot += __shfl_xor(tot, 32);
        float rs = 1.0f / tot;
        long row = (long)(l0w + g * 16 + c) * 4 + b;
#pragma unroll
        for (int s = 0; s < 4; ++s) {
            bf16x4 ov;
#pragma unroll
            for (int i = 0; i < 4; ++i) ov[i] = (__bf16)(O[g][s][i] * rs);
            *(bf16x4*)&O_flat[row * 1024 + h * 64 + 16 * s + 4 * q] = ov;
        }
    }
}

// ---------------- launch ----------------
extern "C" void kernel_launch(void* const* d_in, const int* in_sizes, int n_in,
                              void* d_out, int out_size, void* d_ws, size_t ws_size,
                              hipStream_t stream) {
    const float* query  = (const float*)d_in[0];
    const float* relpos = (const float*)d_in[1];
    const float* w_in   = (const float*)d_in[2];
    const float* b_in   = (const float*)d_in[3];
    const float* w_out  = (const float*)d_in[4];
    const float* b_out  = (const float*)d_in[5];
    float* out = (float*)d_out;

    char* ws = (char*)d_ws;
    size_t off = 0;
    auto alloc = [&](size_t bytes) {
        void* p = ws + off;
        off += (bytes + 255) & ~(size_t)255;
        return p;
    };
    __bf16* qA    = (__bf16*)alloc((size_t)M1 * EE * 2);        // query bf16
    __bf16* winb  = (__bf16*)alloc((size_t)3 * EE * EE * 2);    // in_proj_weight bf16
    __bf16* woutb = (__bf16*)alloc((size_t)EE * EE * 2);        // out_proj_weight bf16
    __bf16* erfp  = (__bf16*)alloc((size_t)SL * DD * 2);        // flipped er bf16
    __bf16* q_ws  = (__bf16*)alloc((size_t)BHC * SL * DD * 2);
    __bf16* k_ws  = (__bf16*)alloc((size_t)BHC * SL * DD * 2);
    __bf16* vT_ws = (__bf16*)alloc((size_t)BHC * SL * DD * 2);
    __bf16* O_flat= (__bf16*)alloc((size_t)M1 * EE * 2);

    // fused conversions + er flip (one launch)
    prep_k<<<8256, 256, 0, stream>>>(query, w_in, w_out, relpos,
                                     qA, winb, woutb, erfp);

    // qkv projection: M=4096, N=3072, K=1024 (v written directly transposed)
    gemm_bt<<<(3072 / BNt) * (M1 / BMt), 256, 0, stream>>>(
        qA, winb, b_in, M1, 3072, EE, 0, q_ws, k_ws, vT_ws, nullptr);

    attn_kernel<<<512, 256, 0, stream>>>(q_ws, k_ws, vT_ws, erfp, O_flat);

    // out projection: M=4096, N=1024, K=1024
    gemm_bt<<<(1024 / BNt) * (M1 / BMt), 256, 0, stream>>>(
        O_flat, woutb, b_out, M1, 1024, EE, 1, nullptr, nullptr, nullptr, out);
}

// Round 9
// 204.961 us; speedup vs baseline: 1.0796x; 1.0796x over previous
//
#include <hip/hip_runtime.h>
#include <hip/hip_bf16.h>

// Problem constants (L=1024, B=4, E=1024, H=16, D=64)
#define SL 1024
#define BB 4
#define EE 1024
#define HH 16
#define DD 64
#define BHC 64          // BB*HH
#define M1 4096         // SL*BB

typedef __bf16 bf16x8 __attribute__((ext_vector_type(8)));
typedef __bf16 bf16x4 __attribute__((ext_vector_type(4)));
typedef float f32x4 __attribute__((ext_vector_type(4)));

typedef __attribute__((address_space(3))) unsigned int lds_u32;
typedef const __attribute__((address_space(1))) unsigned int g_u32;

__device__ __forceinline__ f32x4 mfma16(bf16x8 a, bf16x8 b, f32x4 c) {
    return __builtin_amdgcn_mfma_f32_16x16x32_bf16(a, b, c, 0, 0, 0);
}

// swizzled frag read: tile stored as 16B chunks with ch' = ch ^ (row&7)
#define FR(buf, row, chunk) (*(const bf16x8*)&(buf)[(row) * 64 + (((chunk) ^ ((row) & 7))) * 8])

// ---------------- fused prep: all f32->bf16 conversions + er flip ----------
__global__ __launch_bounds__(256) void prep_k(const float* __restrict__ query,
                                              const float* __restrict__ w_in,
                                              const float* __restrict__ w_out,
                                              const float* __restrict__ rel,
                                              __bf16* __restrict__ qA,
                                              __bf16* __restrict__ winb,
                                              __bf16* __restrict__ woutb,
                                              __bf16* __restrict__ erfp) {
    int bid = blockIdx.x, tid = threadIdx.x;
    const float* src;
    __bf16* dst;
    int idx;
    if (bid < 4096)      { src = query; dst = qA;    idx = (bid * 256 + tid) * 4; }
    else if (bid < 7168) { src = w_in;  dst = winb;  idx = ((bid - 4096) * 256 + tid) * 4; }
    else if (bid < 8192) { src = w_out; dst = woutb; idx = ((bid - 7168) * 256 + tid) * 4; }
    else {
        int e4 = ((bid - 8192) * 256 + tid) * 4;
        int r = e4 >> 6, d = e4 & 63;
        float4 v = *(const float4*)&rel[(1023 - r) * 64 + d];
        bf16x4 o;
        o[0] = (__bf16)v.x; o[1] = (__bf16)v.y; o[2] = (__bf16)v.z; o[3] = (__bf16)v.w;
        *(bf16x4*)&erfp[e4] = o;
        return;
    }
    float4 v = *(const float4*)&src[idx];
    bf16x4 o;
    o[0] = (__bf16)v.x; o[1] = (__bf16)v.y; o[2] = (__bf16)v.z; o[3] = (__bf16)v.w;
    *(bf16x4*)&dst[idx] = o;
}

// ---------------- qkv GEMM: C = A(MxK) @ B(NxK)^T + bias, repack epilogue ---
#define BMt 128
#define BNt 128
#define BKt 32
__global__ __launch_bounds__(256) void gemm_qkv(const __bf16* __restrict__ A,
                                                const __bf16* __restrict__ Bm,
                                                const float* __restrict__ bias,
                                                __bf16* __restrict__ q_ws,
                                                __bf16* __restrict__ k_ws,
                                                __bf16* __restrict__ vT_ws) {
    const int M = M1, N = 3072, K = EE;
    __shared__ __bf16 As[BMt * BKt];
    __shared__ __bf16 Bs[BNt * BKt];
    int tid = threadIdx.x;
    int wave = tid >> 6, lane = tid & 63;
    int quad = lane >> 4, c = lane & 15;
    int ntiles = N / BNt;
    int bx = blockIdx.x % ntiles, by = blockIdx.x / ntiles;
    int m0 = by * BMt, n0 = bx * BNt;
    int wm = (wave >> 1) * 64, wn = (wave & 1) * 64;
    int srow = lane >> 2, scol = (lane & 3) * 8;

    f32x4 acc[4][4] = {};
    for (int k0 = 0; k0 < K; k0 += BKt) {
        __syncthreads();
#pragma unroll
        for (int n = 0; n < 2; ++n) {
            int r0 = 32 * wave + 16 * n;
            const __bf16* ga = &A[(long)(m0 + r0 + srow) * K + k0 + scol];
            const __bf16* gb = &Bm[(long)(n0 + r0 + srow) * K + k0 + scol];
            __builtin_amdgcn_global_load_lds((g_u32*)ga, (lds_u32*)&As[r0 * BKt], 16, 0, 0);
            __builtin_amdgcn_global_load_lds((g_u32*)gb, (lds_u32*)&Bs[r0 * BKt], 16, 0, 0);
        }
        __syncthreads();
        bf16x8 af[4], bfr[4];
#pragma unroll
        for (int t = 0; t < 4; ++t) {
            af[t]  = *(const bf16x8*)&As[(wm + t * 16 + c) * BKt + quad * 8];
            bfr[t] = *(const bf16x8*)&Bs[(wn + t * 16 + c) * BKt + quad * 8];
        }
#pragma unroll
        for (int mt = 0; mt < 4; ++mt)
#pragma unroll
            for (int nt = 0; nt < 4; ++nt)
                acc[mt][nt] = mfma16(af[mt], bfr[nt], acc[mt][nt]);
    }
    // LDS repack epilogue. Per-wave slab 16 x 72 in As/Bs (after sync).
    __syncthreads();
    __bf16* slab = ((wave < 2) ? As : Bs) + (wave & 1) * 2048;
    int nnb = n0 + wn;                 // wave's 64-col block: d = 16*nt + c
    int which = nnb >> 10;             // 0=q 1=k 2=v (uniform per wave)
    int hh = (nnb & 1023) >> 6;        // head (uniform per wave)
    float scale = (which == 0) ? 0.125f : 1.0f;
#pragma unroll
    for (int mt = 0; mt < 4; ++mt) {
#pragma unroll
        for (int nt = 0; nt < 4; ++nt) {
            float bv = bias[nnb + nt * 16 + c];
#pragma unroll
            for (int i = 0; i < 4; ++i)
                slab[(quad * 4 + i) * 72 + nt * 16 + c] =
                    (__bf16)((acc[mt][nt][i] + bv) * scale);
        }
        // intra-wave write->read: ordered via lgkmcnt, no barrier needed
        if (which < 2) {
            int mm = m0 + wm + mt * 16 + c;        // lane owns row c of the tile
            int l = mm >> 2, bb = mm & 3;
            __bf16* dstp = ((which == 0) ? q_ws : k_ws) +
                           ((long)(bb * 16 + hh) * 1024 + l) * 64;
            bf16x8 t0 = *(const bf16x8*)&slab[c * 72 + quad * 8];
            bf16x8 t1 = *(const bf16x8*)&slab[c * 72 + 32 + quad * 8];
            *(bf16x8*)&dstp[quad * 8] = t0;
            *(bf16x8*)&dstp[32 + quad * 8] = t1;
        } else {
            int d = quad * 16 + c;                 // lane owns one d column
            __bf16 tmp[16];
#pragma unroll
            for (int jr = 0; jr < 16; ++jr) tmp[jr] = slab[jr * 72 + d];
            int L0 = (m0 + wm + mt * 16) >> 2;     // 4 consecutive l per b
#pragma unroll
            for (int bs = 0; bs < 4; ++bs) {
                bf16x4 pk;
                pk[0] = tmp[bs]; pk[1] = tmp[4 + bs];
                pk[2] = tmp[8 + bs]; pk[3] = tmp[12 + bs];
                *(bf16x4*)&vT_ws[((long)(bs * 16 + hh) * 64 + d) * 1024 + L0] = pk;
            }
        }
    }
}

// ---------------- out-proj GEMM: 128x64 tile -> 512 blocks = 2/CU -----------
// (round-8 analysis: 256-block out-proj ran at 1 block/CU with fully exposed
// barrier drains; halving BN doubles resident blocks.)
__global__ __launch_bounds__(256) void gemm_out(const __bf16* __restrict__ A,
                                                const __bf16* __restrict__ Bm,
                                                const float* __restrict__ bias,
                                                float* __restrict__ outf) {
    const int N = 1024, K = EE;
    __shared__ __bf16 As[BMt * BKt];   // 128 x 32
    __shared__ __bf16 Bs[64 * BKt];    // 64 x 32
    int tid = threadIdx.x;
    int wave = tid >> 6, lane = tid & 63;
    int quad = lane >> 4, c = lane & 15;
    int bx = blockIdx.x & 15, by = blockIdx.x >> 4;   // 16 x 32 tiles
    int m0 = by * BMt, n0 = bx * 64;
    int wm = (wave >> 1) * 64, wn = (wave & 1) * 32;
    int srow = lane >> 2, scol = (lane & 3) * 8;

    f32x4 acc[4][2] = {};
    for (int k0 = 0; k0 < K; k0 += BKt) {
        __syncthreads();
#pragma unroll
        for (int n = 0; n < 2; ++n) {
            int r0 = 32 * wave + 16 * n;
            const __bf16* ga = &A[(long)(m0 + r0 + srow) * K + k0 + scol];
            __builtin_amdgcn_global_load_lds((g_u32*)ga, (lds_u32*)&As[r0 * BKt], 16, 0, 0);
        }
        {
            int r0 = 16 * wave;
            const __bf16* gb = &Bm[(long)(n0 + r0 + srow) * K + k0 + scol];
            __builtin_amdgcn_global_load_lds((g_u32*)gb, (lds_u32*)&Bs[r0 * BKt], 16, 0, 0);
        }
        __syncthreads();
        bf16x8 af[4], bfr[2];
#pragma unroll
        for (int t = 0; t < 4; ++t)
            af[t] = *(const bf16x8*)&As[(wm + t * 16 + c) * BKt + quad * 8];
#pragma unroll
        for (int t = 0; t < 2; ++t)
            bfr[t] = *(const bf16x8*)&Bs[(wn + t * 16 + c) * BKt + quad * 8];
#pragma unroll
        for (int mt = 0; mt < 4; ++mt)
#pragma unroll
            for (int nt = 0; nt < 2; ++nt)
                acc[mt][nt] = mfma16(af[mt], bfr[nt], acc[mt][nt]);
    }
#pragma unroll
    for (int mt = 0; mt < 4; ++mt)
#pragma unroll
        for (int nt = 0; nt < 2; ++nt) {
            int nn = n0 + wn + nt * 16 + c;
            float bv = bias[nn];
#pragma unroll
            for (int i = 0; i < 4; ++i) {
                int mm = m0 + wm + mt * 16 + quad * 4 + i;
                outf[(long)mm * N + nn] = acc[mt][nt][i] + bv;
            }
        }
}

// ---------------- attention (round-7 structure, proven 66.7us) --------------
// grid 512 (64 bh x 8 tiles of 128 l-rows, XCD swizzle), block 256 = 4 waves,
// wave owns 32 rows as TWO 16-row groups sharing K/V/E A-frags. K dist-1
// double-buffered; V dist-0 single; erf parity-ring dist-0 (consumed after
// mid-round barrier). Rel ring 2 slots/wave; P reuses the dead slot.
// No softmax max-subtraction (|S| bounded by construction).
#define RSTn 72
#define RSLOT (32 * RSTn)
__global__ __launch_bounds__(256, 2) void attn_kernel(const __bf16* __restrict__ q_ws,
                                                      const __bf16* __restrict__ k_ws,
                                                      const __bf16* __restrict__ vT_ws,
                                                      const __bf16* __restrict__ erf,
                                                      __bf16* __restrict__ O_flat) {
    __shared__ __bf16 Ks[2][4096];       // 16 KB  K tiles (double)
    __shared__ __bf16 Vs[4096];          // 8 KB   V^T tile (single, dist-0)
    __shared__ __bf16 Es[2][4096];       // 16 KB  erf tiles (parity ring)
    __shared__ __bf16 Ring[4][2][RSLOT]; // 36.9 KB rel ring + P (dead slot)

    int tid = threadIdx.x;
    int w = tid >> 6, lane = tid & 63;
    int q = lane >> 4, c = lane & 15;
    int bid = blockIdx.x;
    int x = bid & 7, ii = bid >> 3;           // XCD-localized swizzle
    int bh = x * 8 + (ii >> 3);
    int blk_l0 = (ii & 7) * 128;
    int b = bh >> 4, h = bh & 15;
    int l0w = blk_l0 + w * 32;

    __bf16* RW = &Ring[w][0][0];

    const __bf16* qp = q_ws + ((long)bh * 1024 + l0w) * 64;
    bf16x8 qf0[2], qf1[2];
    qf0[0] = *(const bf16x8*)&qp[c * 64 + q * 8];
    qf1[0] = *(const bf16x8*)&qp[c * 64 + 32 + q * 8];
    qf0[1] = *(const bf16x8*)&qp[(16 + c) * 64 + q * 8];
    qf1[1] = *(const bf16x8*)&qp[(16 + c) * 64 + 32 + q * 8];

    const __bf16* kbase = k_ws + (long)bh * 65536;
    const __bf16* vbase = vT_ws + (long)bh * 65536;

    // staging geometry: wave w covers chunk slots [128w, 128w+128)
    int sr[2], sc[2], ldo[2];
#pragma unroll
    for (int n = 0; n < 2; ++n) {
        int sidx = w * 128 + n * 64 + lane;
        sr[n] = sidx >> 3;
        sc[n] = (sidx & 7) ^ (sr[n] & 7);
        ldo[n] = (w * 128 + n * 64) * 8;
    }

    // prologue: K tile 15 -> Ks[1]
#pragma unroll
    for (int n = 0; n < 2; ++n)
        __builtin_amdgcn_global_load_lds((g_u32*)(kbase + 15 * 4096 + sr[n] * 64 + sc[n] * 8),
                                         (lds_u32*)&Ks[1][ldo[n]], 16, 0, 0);
    __syncthreads();

    f32x4 O[2][4] = {};
    float l_run[2] = {0.f, 0.f};

    for (int kt = 15; kt >= 0; --kt) {
        int p = kt & 1;
        // ---- DMA issues (drained at barrier #1) ----
        if (kt > 0) {
#pragma unroll
            for (int n = 0; n < 2; ++n)
                __builtin_amdgcn_global_load_lds(
                    (g_u32*)(kbase + (kt - 1) * 4096 + sr[n] * 64 + sc[n] * 8),
                    (lds_u32*)&Ks[p ^ 1][ldo[n]], 16, 0, 0);
        }
#pragma unroll
        for (int n = 0; n < 2; ++n)
            __builtin_amdgcn_global_load_lds(
                (g_u32*)(vbase + sr[n] * 1024 + kt * 64 + sc[n] * 8),
                (lds_u32*)&Vs[ldo[n]], 16, 0, 0);
        int rmaxB = blk_l0 + 127 - kt * 64;       // block's new erf tile tB
        if (rmaxB >= 0) {
            int tB = rmaxB >> 6;
#pragma unroll
            for (int n = 0; n < 2; ++n)
                __builtin_amdgcn_global_load_lds(
                    (g_u32*)(erf + tB * 4096 + sr[n] * 64 + sc[n] * 8),
                    (lds_u32*)&Es[tB & 1][ldo[n]], 16, 0, 0);
        }
        // ---- S^T = K Q^T (K frags read once, used by both groups) ----
        const __bf16* Kp = Ks[p];
        bf16x8 ka0[4], ka1[4];
#pragma unroll
        for (int s = 0; s < 4; ++s) {
            int row = 16 * s + c;
            ka0[s] = FR(Kp, row, q);
            ka1[s] = FR(Kp, row, 4 + q);
        }
        f32x4 S[2][4];
#pragma unroll
        for (int g = 0; g < 2; ++g)
#pragma unroll
            for (int s = 0; s < 4; ++s) {
                f32x4 acc = {0.f, 0.f, 0.f, 0.f};
                acc = mfma16(ka0[s], qf0[g], acc);
                acc = mfma16(ka1[s], qf1[g], acc);
                S[g][s] = acc;
            }
        __syncthreads();   // barrier #1: this round's V/E (and next K) landed
        // ---- R phase: wave's new rel tile t1 = (l0w+31-kt*64)>>6 ----
        int rmax = l0w + 31 - kt * 64;
        int t1 = rmax >> 6;
        if (rmax >= 0) {
            const __bf16* Ep = Es[t1 & 1];
            bf16x8 ea0[4], ea1[4];
#pragma unroll
            for (int s = 0; s < 4; ++s) {
                int row = 16 * s + c;
                ea0[s] = FR(Ep, row, q);
                ea1[s] = FR(Ep, row, 4 + q);
            }
            __bf16* rt = RW + (t1 & 1) * RSLOT;
#pragma unroll
            for (int g = 0; g < 2; ++g)
#pragma unroll
                for (int s = 0; s < 4; ++s) {
                    f32x4 ar = {0.f, 0.f, 0.f, 0.f};
                    ar = mfma16(ea0[s], qf0[g], ar);
                    ar = mfma16(ea1[s], qf1[g], ar);
                    bf16x4 pk;
#pragma unroll
                    for (int i = 0; i < 4; ++i) pk[i] = (__bf16)ar[i];
                    *(bf16x4*)&rt[(g * 16 + c) * RSTn + 16 * s + 4 * q] = pk;
                }
            // gather: r = l - m; resident tiles {t1-1, t1} at slot (r>>6)&1
#pragma unroll
            for (int g = 0; g < 2; ++g) {
                int rb = l0w + g * 16 + c - kt * 64 - 4 * q;
#pragma unroll
                for (int s = 0; s < 4; ++s)
#pragma unroll
                    for (int i = 0; i < 4; ++i) {
                        int r = rb - 16 * s - i;
                        if (r >= 0)
                            S[g][s][i] += (float)RW[((r >> 6) & 1) * RSLOT +
                                                    (g * 16 + c) * RSTn + (r & 63)];
                    }
            }
        }
        int pslot = (rmax >= 0) ? ((t1 & 1) ^ 1) : 1;
        // ---- exp (no max) + lane-local sums ----
#pragma unroll
        for (int g = 0; g < 2; ++g) {
            float ps[4];
#pragma unroll
            for (int s = 0; s < 4; ++s) {
                float a = __expf(S[g][s][0]), b2 = __expf(S[g][s][1]);
                float c2 = __expf(S[g][s][2]), d2 = __expf(S[g][s][3]);
                S[g][s][0] = a; S[g][s][1] = b2; S[g][s][2] = c2; S[g][s][3] = d2;
                ps[s] = (a + b2) + (c2 + d2);
            }
            l_run[g] += (ps[0] + ps[1]) + (ps[2] + ps[3]);
        }
        // ---- P into ring's dead slot (b64 packed) ----
        __bf16* PW = RW + pslot * RSLOT;
#pragma unroll
        for (int g = 0; g < 2; ++g)
#pragma unroll
            for (int s = 0; s < 4; ++s) {
                bf16x4 pk;
#pragma unroll
                for (int i = 0; i < 4; ++i) pk[i] = (__bf16)S[g][s][i];
                *(bf16x4*)&PW[(g * 16 + c) * RSTn + 16 * s + 4 * q] = pk;
            }
        // ---- O^T += V^T P^T (V frags read once, both groups) ----
        bf16x8 va0[4], va1[4];
#pragma unroll
        for (int s = 0; s < 4; ++s) {
            int row = 16 * s + c;
            va0[s] = FR(Vs, row, q);
            va1[s] = FR(Vs, row, 4 + q);
        }
        bf16x8 pa0[2], pa1[2];
#pragma unroll
        for (int g = 0; g < 2; ++g) {
            pa0[g] = *(const bf16x8*)&PW[(g * 16 + c) * RSTn + q * 8];
            pa1[g] = *(const bf16x8*)&PW[(g * 16 + c) * RSTn + 32 + q * 8];
        }
#pragma unroll
        for (int g = 0; g < 2; ++g)
#pragma unroll
            for (int s = 0; s < 4; ++s) {
                O[g][s] = mfma16(va0[s], pa0[g], O[g][s]);
                O[g][s] = mfma16(va1[s], pa1[g], O[g][s]);
            }
        __syncthreads();   // barrier #2: guards Vs/Ks reuse next round
    }
    // ---- epilogue ----
#pragma unroll
    for (int g = 0; g < 2; ++g) {
        float tot = l_run[g];
        tot += __shfl_xor(tot, 16);
        tot += __shfl_xor(tot, 32);
        float rs = 1.0f / tot;
        long row = (long)(l0w + g * 16 + c) * 4 + b;
#pragma unroll
        for (int s = 0; s < 4; ++s) {
            bf16x4 ov;
#pragma unroll
            for (int i = 0; i < 4; ++i) ov[i] = (__bf16)(O[g][s][i] * rs);
            *(bf16x4*)&O_flat[row * 1024 + h * 64 + 16 * s + 4 * q] = ov;
        }
    }
}

// ---------------- launch ----------------
extern "C" void kernel_launch(void* const* d_in, const int* in_sizes, int n_in,
                              void* d_out, int out_size, void* d_ws, size_t ws_size,
                              hipStream_t stream) {
    const float* query  = (const float*)d_in[0];
    const float* relpos = (const float*)d_in[1];
    const float* w_in   = (const float*)d_in[2];
    const float* b_in   = (const float*)d_in[3];
    const float* w_out  = (const float*)d_in[4];
    const float* b_out  = (const float*)d_in[5];
    float* out = (float*)d_out;

    char* ws = (char*)d_ws;
    size_t off = 0;
    auto alloc = [&](size_t bytes) {
        void* p = ws + off;
        off += (bytes + 255) & ~(size_t)255;
        return p;
    };
    __bf16* qA    = (__bf16*)alloc((size_t)M1 * EE * 2);        // query bf16
    __bf16* winb  = (__bf16*)alloc((size_t)3 * EE * EE * 2);    // in_proj_weight bf16
    __bf16* woutb = (__bf16*)alloc((size_t)EE * EE * 2);        // out_proj_weight bf16
    __bf16* erfp  = (__bf16*)alloc((size_t)SL * DD * 2);        // flipped er bf16
    __bf16* q_ws  = (__bf16*)alloc((size_t)BHC * SL * DD * 2);
    __bf16* k_ws  = (__bf16*)alloc((size_t)BHC * SL * DD * 2);
    __bf16* vT_ws = (__bf16*)alloc((size_t)BHC * SL * DD * 2);
    __bf16* O_flat= (__bf16*)alloc((size_t)M1 * EE * 2);

    // fused conversions + er flip (one launch)
    prep_k<<<8256, 256, 0, stream>>>(query, w_in, w_out, relpos,
                                     qA, winb, woutb, erfp);

    // qkv projection: M=4096, N=3072, K=1024 (v written directly transposed)
    gemm_qkv<<<(3072 / BNt) * (M1 / BMt), 256, 0, stream>>>(
        qA, winb, b_in, q_ws, k_ws, vT_ws);

    attn_kernel<<<512, 256, 0, stream>>>(q_ws, k_ws, vT_ws, erfp, O_flat);

    // out projection: M=4096, N=1024, K=1024; 128x64 tiles -> 512 blocks
    gemm_out<<<512, 256, 0, stream>>>(O_flat, woutb, b_out, out);
}

// Round 10
// 190.961 us; speedup vs baseline: 1.1588x; 1.0733x over previous
//
#include <hip/hip_runtime.h>
#include <hip/hip_bf16.h>

// Problem constants (L=1024, B=4, E=1024, H=16, D=64)
#define SL 1024
#define BB 4
#define EE 1024
#define HH 16
#define DD 64
#define BHC 64          // BB*HH
#define M1 4096         // SL*BB

typedef __bf16 bf16x8 __attribute__((ext_vector_type(8)));
typedef __bf16 bf16x4 __attribute__((ext_vector_type(4)));
typedef float f32x4 __attribute__((ext_vector_type(4)));

typedef __attribute__((address_space(3))) unsigned int lds_u32;
typedef const __attribute__((address_space(1))) unsigned int g_u32;

__device__ __forceinline__ f32x4 mfma16(bf16x8 a, bf16x8 b, f32x4 c) {
    return __builtin_amdgcn_mfma_f32_16x16x32_bf16(a, b, c, 0, 0, 0);
}

__device__ __forceinline__ float fexp2(float x) {
#if __has_builtin(__builtin_amdgcn_exp2f)
    return __builtin_amdgcn_exp2f(x);
#else
    return exp2f(x);
#endif
}

// swizzled frag read: tile stored as 16B chunks with ch' = ch ^ (row&7)
#define FR(buf, row, chunk) (*(const bf16x8*)&(buf)[(row) * 64 + (((chunk) ^ ((row) & 7))) * 8])

// ---------------- fused prep: all f32->bf16 conversions + er flip ----------
__global__ __launch_bounds__(256) void prep_k(const float* __restrict__ query,
                                              const float* __restrict__ w_in,
                                              const float* __restrict__ w_out,
                                              const float* __restrict__ rel,
                                              __bf16* __restrict__ qA,
                                              __bf16* __restrict__ winb,
                                              __bf16* __restrict__ woutb,
                                              __bf16* __restrict__ erfp) {
    int bid = blockIdx.x, tid = threadIdx.x;
    const float* src;
    __bf16* dst;
    int idx;
    if (bid < 4096)      { src = query; dst = qA;    idx = (bid * 256 + tid) * 4; }
    else if (bid < 7168) { src = w_in;  dst = winb;  idx = ((bid - 4096) * 256 + tid) * 4; }
    else if (bid < 8192) { src = w_out; dst = woutb; idx = ((bid - 7168) * 256 + tid) * 4; }
    else {
        int e4 = ((bid - 8192) * 256 + tid) * 4;
        int r = e4 >> 6, d = e4 & 63;
        float4 v = *(const float4*)&rel[(1023 - r) * 64 + d];
        bf16x4 o;
        o[0] = (__bf16)v.x; o[1] = (__bf16)v.y; o[2] = (__bf16)v.z; o[3] = (__bf16)v.w;
        *(bf16x4*)&erfp[e4] = o;
        return;
    }
    float4 v = *(const float4*)&src[idx];
    bf16x4 o;
    o[0] = (__bf16)v.x; o[1] = (__bf16)v.y; o[2] = (__bf16)v.z; o[3] = (__bf16)v.w;
    *(bf16x4*)&dst[idx] = o;
}

// ---------------- qkv GEMM: C = A(MxK) @ B(NxK)^T + bias, repack epilogue ---
// q pre-scaled by log2(e)/8 so the attention softmax can use raw v_exp_f32
// (exp2) with no per-element multiply.
#define BMt 128
#define BNt 128
#define BKt 32
__global__ __launch_bounds__(256) void gemm_qkv(const __bf16* __restrict__ A,
                                                const __bf16* __restrict__ Bm,
                                                const float* __restrict__ bias,
                                                __bf16* __restrict__ q_ws,
                                                __bf16* __restrict__ k_ws,
                                                __bf16* __restrict__ vT_ws) {
    const int M = M1, N = 3072, K = EE;
    __shared__ __bf16 As[BMt * BKt];
    __shared__ __bf16 Bs[BNt * BKt];
    int tid = threadIdx.x;
    int wave = tid >> 6, lane = tid & 63;
    int quad = lane >> 4, c = lane & 15;
    int ntiles = N / BNt;
    int bx = blockIdx.x % ntiles, by = blockIdx.x / ntiles;
    int m0 = by * BMt, n0 = bx * BNt;
    int wm = (wave >> 1) * 64, wn = (wave & 1) * 64;
    int srow = lane >> 2, scol = (lane & 3) * 8;

    f32x4 acc[4][4] = {};
    for (int k0 = 0; k0 < K; k0 += BKt) {
        __syncthreads();
#pragma unroll
        for (int n = 0; n < 2; ++n) {
            int r0 = 32 * wave + 16 * n;
            const __bf16* ga = &A[(long)(m0 + r0 + srow) * K + k0 + scol];
            const __bf16* gb = &Bm[(long)(n0 + r0 + srow) * K + k0 + scol];
            __builtin_amdgcn_global_load_lds((g_u32*)ga, (lds_u32*)&As[r0 * BKt], 16, 0, 0);
            __builtin_amdgcn_global_load_lds((g_u32*)gb, (lds_u32*)&Bs[r0 * BKt], 16, 0, 0);
        }
        __syncthreads();
        bf16x8 af[4], bfr[4];
#pragma unroll
        for (int t = 0; t < 4; ++t) {
            af[t]  = *(const bf16x8*)&As[(wm + t * 16 + c) * BKt + quad * 8];
            bfr[t] = *(const bf16x8*)&Bs[(wn + t * 16 + c) * BKt + quad * 8];
        }
#pragma unroll
        for (int mt = 0; mt < 4; ++mt)
#pragma unroll
            for (int nt = 0; nt < 4; ++nt)
                acc[mt][nt] = mfma16(af[mt], bfr[nt], acc[mt][nt]);
    }
    // LDS repack epilogue. Per-wave slab 16 x 72 in As/Bs (after sync).
    __syncthreads();
    __bf16* slab = ((wave < 2) ? As : Bs) + (wave & 1) * 2048;
    int nnb = n0 + wn;                 // wave's 64-col block: d = 16*nt + c
    int which = nnb >> 10;             // 0=q 1=k 2=v (uniform per wave)
    int hh = (nnb & 1023) >> 6;        // head (uniform per wave)
    // q scale folds 1/sqrt(D)=0.125 AND log2(e) for the exp2-domain softmax
    float scale = (which == 0) ? (0.125f * 1.44269504f) : 1.0f;
#pragma unroll
    for (int mt = 0; mt < 4; ++mt) {
#pragma unroll
        for (int nt = 0; nt < 4; ++nt) {
            float bv = bias[nnb + nt * 16 + c];
#pragma unroll
            for (int i = 0; i < 4; ++i)
                slab[(quad * 4 + i) * 72 + nt * 16 + c] =
                    (__bf16)((acc[mt][nt][i] + bv) * scale);
        }
        // intra-wave write->read: ordered via lgkmcnt, no barrier needed
        if (which < 2) {
            int mm = m0 + wm + mt * 16 + c;        // lane owns row c of the tile
            int l = mm >> 2, bb = mm & 3;
            __bf16* dstp = ((which == 0) ? q_ws : k_ws) +
                           ((long)(bb * 16 + hh) * 1024 + l) * 64;
            bf16x8 t0 = *(const bf16x8*)&slab[c * 72 + quad * 8];
            bf16x8 t1 = *(const bf16x8*)&slab[c * 72 + 32 + quad * 8];
            *(bf16x8*)&dstp[quad * 8] = t0;
            *(bf16x8*)&dstp[32 + quad * 8] = t1;
        } else {
            int d = quad * 16 + c;                 // lane owns one d column
            __bf16 tmp[16];
#pragma unroll
            for (int jr = 0; jr < 16; ++jr) tmp[jr] = slab[jr * 72 + d];
            int L0 = (m0 + wm + mt * 16) >> 2;     // 4 consecutive l per b
#pragma unroll
            for (int bs = 0; bs < 4; ++bs) {
                bf16x4 pk;
                pk[0] = tmp[bs]; pk[1] = tmp[4 + bs];
                pk[2] = tmp[8 + bs]; pk[3] = tmp[12 + bs];
                *(bf16x4*)&vT_ws[((long)(bs * 16 + hh) * 64 + d) * 1024 + L0] = pk;
            }
        }
    }
}

// ---------------- out-proj GEMM: 128x64 tile -> 512 blocks = 2/CU -----------
__global__ __launch_bounds__(256) void gemm_out(const __bf16* __restrict__ A,
                                                const __bf16* __restrict__ Bm,
                                                const float* __restrict__ bias,
                                                float* __restrict__ outf) {
    const int N = 1024, K = EE;
    __shared__ __bf16 As[BMt * BKt];   // 128 x 32
    __shared__ __bf16 Bs[64 * BKt];    // 64 x 32
    int tid = threadIdx.x;
    int wave = tid >> 6, lane = tid & 63;
    int quad = lane >> 4, c = lane & 15;
    int bx = blockIdx.x & 15, by = blockIdx.x >> 4;   // 16 x 32 tiles
    int m0 = by * BMt, n0 = bx * 64;
    int wm = (wave >> 1) * 64, wn = (wave & 1) * 32;
    int srow = lane >> 2, scol = (lane & 3) * 8;

    f32x4 acc[4][2] = {};
    for (int k0 = 0; k0 < K; k0 += BKt) {
        __syncthreads();
#pragma unroll
        for (int n = 0; n < 2; ++n) {
            int r0 = 32 * wave + 16 * n;
            const __bf16* ga = &A[(long)(m0 + r0 + srow) * K + k0 + scol];
            __builtin_amdgcn_global_load_lds((g_u32*)ga, (lds_u32*)&As[r0 * BKt], 16, 0, 0);
        }
        {
            int r0 = 16 * wave;
            const __bf16* gb = &Bm[(long)(n0 + r0 + srow) * K + k0 + scol];
            __builtin_amdgcn_global_load_lds((g_u32*)gb, (lds_u32*)&Bs[r0 * BKt], 16, 0, 0);
        }
        __syncthreads();
        bf16x8 af[4], bfr[2];
#pragma unroll
        for (int t = 0; t < 4; ++t)
            af[t] = *(const bf16x8*)&As[(wm + t * 16 + c) * BKt + quad * 8];
#pragma unroll
        for (int t = 0; t < 2; ++t)
            bfr[t] = *(const bf16x8*)&Bs[(wn + t * 16 + c) * BKt + quad * 8];
#pragma unroll
        for (int mt = 0; mt < 4; ++mt)
#pragma unroll
            for (int nt = 0; nt < 2; ++nt)
                acc[mt][nt] = mfma16(af[mt], bfr[nt], acc[mt][nt]);
    }
#pragma unroll
    for (int mt = 0; mt < 4; ++mt)
#pragma unroll
        for (int nt = 0; nt < 2; ++nt) {
            int nn = n0 + wn + nt * 16 + c;
            float bv = bias[nn];
#pragma unroll
            for (int i = 0; i < 4; ++i) {
                int mm = m0 + wm + mt * 16 + quad * 4 + i;
                outf[(long)mm * N + nn] = acc[mt][nt][i] + bv;
            }
        }
}

// ---------------- attention (r7 structure + VALU surgery) --------------------
// grid 512 (64 bh x 8 tiles of 128 l-rows, XCD swizzle), block 256 = 4 waves,
// wave owns 32 rows as TWO 16-row groups sharing K/V/E A-frags. K dist-1
// double-buffered; V dist-0 single; erf parity-ring dist-0 (consumed after
// mid-round barrier).
// VALU surgery vs r7/r9:
//  - scores arrive in log2-domain (q pre-scaled by log2e in gemm_qkv) ->
//    raw v_exp_f32 via fexp2, no per-element mul.
//  - rel ring stored mod-128 contiguous [l][r & 127]: gather addr = AND+ADD
//    (no slot-select shift/mul). P reuses the dead 64-half (gather precedes
//    P write in wave-local program order; next round's R overwrites P after
//    pa reads - all wave-local, no barrier interplay).
//  - interior rounds (whole r-window >= 0, wave-uniform) drop per-element
//    guards.
#define RST2 136   // ring row stride (halfwords): 128 payload + 8 pad, 272 B
__global__ __launch_bounds__(256, 2) void attn_kernel(const __bf16* __restrict__ q_ws,
                                                      const __bf16* __restrict__ k_ws,
                                                      const __bf16* __restrict__ vT_ws,
                                                      const __bf16* __restrict__ erf,
                                                      __bf16* __restrict__ O_flat) {
    __shared__ __bf16 Ks[2][4096];       // 16 KB  K tiles (double)
    __shared__ __bf16 Vs[4096];          // 8 KB   V^T tile (single, dist-0)
    __shared__ __bf16 Es[2][4096];       // 16 KB  erf tiles (parity ring)
    __shared__ __bf16 Ring[4][32 * RST2];// 34 KB  per-wave mod-128 rel ring + P

    int tid = threadIdx.x;
    int w = tid >> 6, lane = tid & 63;
    int q = lane >> 4, c = lane & 15;
    int bid = blockIdx.x;
    int x = bid & 7, ii = bid >> 3;           // XCD-localized swizzle
    int bh = x * 8 + (ii >> 3);
    int blk_l0 = (ii & 7) * 128;
    int b = bh >> 4, h = bh & 15;
    int l0w = blk_l0 + w * 32;

    __bf16* RW = Ring[w];
    int row0 = c * RST2, row1 = (16 + c) * RST2;   // lane's two l-row bases

    const __bf16* qp = q_ws + ((long)bh * 1024 + l0w) * 64;
    bf16x8 qf0[2], qf1[2];
    qf0[0] = *(const bf16x8*)&qp[c * 64 + q * 8];
    qf1[0] = *(const bf16x8*)&qp[c * 64 + 32 + q * 8];
    qf0[1] = *(const bf16x8*)&qp[(16 + c) * 64 + q * 8];
    qf1[1] = *(const bf16x8*)&qp[(16 + c) * 64 + 32 + q * 8];

    const __bf16* kbase = k_ws + (long)bh * 65536;
    const __bf16* vbase = vT_ws + (long)bh * 65536;

    // staging geometry: wave w covers chunk slots [128w, 128w+128)
    int sr[2], sc[2], ldo[2];
#pragma unroll
    for (int n = 0; n < 2; ++n) {
        int sidx = w * 128 + n * 64 + lane;
        sr[n] = sidx >> 3;
        sc[n] = (sidx & 7) ^ (sr[n] & 7);
        ldo[n] = (w * 128 + n * 64) * 8;
    }

    // prologue: K tile 15 -> Ks[1]
#pragma unroll
    for (int n = 0; n < 2; ++n)
        __builtin_amdgcn_global_load_lds((g_u32*)(kbase + 15 * 4096 + sr[n] * 64 + sc[n] * 8),
                                         (lds_u32*)&Ks[1][ldo[n]], 16, 0, 0);
    __syncthreads();

    f32x4 O[2][4] = {};
    float l_run[2] = {0.f, 0.f};

    for (int kt = 15; kt >= 0; --kt) {
        int p = kt & 1;
        // ---- DMA issues (drained at barrier #1) ----
        if (kt > 0) {
#pragma unroll
            for (int n = 0; n < 2; ++n)
                __builtin_amdgcn_global_load_lds(
                    (g_u32*)(kbase + (kt - 1) * 4096 + sr[n] * 64 + sc[n] * 8),
                    (lds_u32*)&Ks[p ^ 1][ldo[n]], 16, 0, 0);
        }
#pragma unroll
        for (int n = 0; n < 2; ++n)
            __builtin_amdgcn_global_load_lds(
                (g_u32*)(vbase + sr[n] * 1024 + kt * 64 + sc[n] * 8),
                (lds_u32*)&Vs[ldo[n]], 16, 0, 0);
        int rmaxB = blk_l0 + 127 - kt * 64;       // block's new erf tile tB
        if (rmaxB >= 0) {
            int tB = rmaxB >> 6;
#pragma unroll
            for (int n = 0; n < 2; ++n)
                __builtin_amdgcn_global_load_lds(
                    (g_u32*)(erf + tB * 4096 + sr[n] * 64 + sc[n] * 8),
                    (lds_u32*)&Es[tB & 1][ldo[n]], 16, 0, 0);
        }
        // ---- S^T = K Q^T (K frags read once, used by both groups) ----
        const __bf16* Kp = Ks[p];
        bf16x8 ka0[4], ka1[4];
#pragma unroll
        for (int s = 0; s < 4; ++s) {
            int row = 16 * s + c;
            ka0[s] = FR(Kp, row, q);
            ka1[s] = FR(Kp, row, 4 + q);
        }
        f32x4 S[2][4];
#pragma unroll
        for (int g = 0; g < 2; ++g)
#pragma unroll
            for (int s = 0; s < 4; ++s) {
                f32x4 acc = {0.f, 0.f, 0.f, 0.f};
                acc = mfma16(ka0[s], qf0[g], acc);
                acc = mfma16(ka1[s], qf1[g], acc);
                S[g][s] = acc;
            }
        __syncthreads();   // barrier #1: this round's V/E (and next K) landed
        // ---- R phase: wave's new rel tile t1 = (l0w+31-kt*64)>>6 ----
        int rmax = l0w + 31 - kt * 64;
        int t1 = rmax >> 6;
        if (rmax >= 0) {
            const __bf16* Ep = Es[t1 & 1];
            bf16x8 ea0[4], ea1[4];
#pragma unroll
            for (int s = 0; s < 4; ++s) {
                int row = 16 * s + c;
                ea0[s] = FR(Ep, row, q);
                ea1[s] = FR(Ep, row, 4 + q);
            }
            int rt = (t1 & 1) * 64;                // mod-128 home of tile t1
#pragma unroll
            for (int g = 0; g < 2; ++g) {
                int rowg = g ? row1 : row0;
#pragma unroll
                for (int s = 0; s < 4; ++s) {
                    f32x4 ar = {0.f, 0.f, 0.f, 0.f};
                    ar = mfma16(ea0[s], qf0[g], ar);
                    ar = mfma16(ea1[s], qf1[g], ar);
                    bf16x4 pk;
#pragma unroll
                    for (int i = 0; i < 4; ++i) pk[i] = (__bf16)ar[i];
                    *(bf16x4*)&RW[rowg + rt + 16 * s + 4 * q] = pk;
                }
            }
            // gather: r = l - m; ring holds tiles {t1-1, t1} at (r & 127)
            int rb0 = l0w + c - kt * 64 - 4 * q;
            if (l0w - kt * 64 - 63 >= 0) {
                // interior: whole window >= 0, no guards
#pragma unroll
                for (int g = 0; g < 2; ++g) {
                    int rowg = g ? row1 : row0;
                    int rbg = rb0 + g * 16;
#pragma unroll
                    for (int s = 0; s < 4; ++s)
#pragma unroll
                        for (int i = 0; i < 4; ++i)
                            S[g][s][i] += (float)RW[rowg + ((rbg - 16 * s - i) & 127)];
                }
            } else {
#pragma unroll
                for (int g = 0; g < 2; ++g) {
                    int rowg = g ? row1 : row0;
                    int rbg = rb0 + g * 16;
#pragma unroll
                    for (int s = 0; s < 4; ++s)
#pragma unroll
                        for (int i = 0; i < 4; ++i) {
                            int r = rbg - 16 * s - i;
                            if (r >= 0)
                                S[g][s][i] += (float)RW[rowg + (r & 127)];
                        }
                }
            }
        }
        int pbase = (rmax >= 0) ? (((t1 & 1) ^ 1) * 64) : 0;   // dead half
        // ---- exp2 (scores already in log2 domain) + lane-local sums ----
#pragma unroll
        for (int g = 0; g < 2; ++g) {
            float ps[4];
#pragma unroll
            for (int s = 0; s < 4; ++s) {
                float a = fexp2(S[g][s][0]), b2 = fexp2(S[g][s][1]);
                float c2 = fexp2(S[g][s][2]), d2 = fexp2(S[g][s][3]);
                S[g][s][0] = a; S[g][s][1] = b2; S[g][s][2] = c2; S[g][s][3] = d2;
                ps[s] = (a + b2) + (c2 + d2);
            }
            l_run[g] += (ps[0] + ps[1]) + (ps[2] + ps[3]);
        }
        // ---- P into ring's dead half (b64 packed) ----
#pragma unroll
        for (int g = 0; g < 2; ++g) {
            int rowg = g ? row1 : row0;
#pragma unroll
            for (int s = 0; s < 4; ++s) {
                bf16x4 pk;
#pragma unroll
                for (int i = 0; i < 4; ++i) pk[i] = (__bf16)S[g][s][i];
                *(bf16x4*)&RW[rowg + pbase + 16 * s + 4 * q] = pk;
            }
        }
        // ---- O^T += V^T P^T (V frags read once, both groups) ----
        bf16x8 va0[4], va1[4];
#pragma unroll
        for (int s = 0; s < 4; ++s) {
            int row = 16 * s + c;
            va0[s] = FR(Vs, row, q);
            va1[s] = FR(Vs, row, 4 + q);
        }
        bf16x8 pa0[2], pa1[2];
#pragma unroll
        for (int g = 0; g < 2; ++g) {
            int rowg = g ? row1 : row0;
            pa0[g] = *(const bf16x8*)&RW[rowg + pbase + q * 8];
            pa1[g] = *(const bf16x8*)&RW[rowg + pbase + 32 + q * 8];
        }
#pragma unroll
        for (int g = 0; g < 2; ++g)
#pragma unroll
            for (int s = 0; s < 4; ++s) {
                O[g][s] = mfma16(va0[s], pa0[g], O[g][s]);
                O[g][s] = mfma16(va1[s], pa1[g], O[g][s]);
            }
        __syncthreads();   // barrier #2: guards Vs/Ks/Es reuse next round
    }
    // ---- epilogue ----
#pragma unroll
    for (int g = 0; g < 2; ++g) {
        float tot = l_run[g];
        tot += __shfl_xor(tot, 16);
        tot += __shfl_xor(tot, 32);
        float rs = 1.0f / tot;
        long row = (long)(l0w + g * 16 + c) * 4 + b;
#pragma unroll
        for (int s = 0; s < 4; ++s) {
            bf16x4 ov;
#pragma unroll
            for (int i = 0; i < 4; ++i) ov[i] = (__bf16)(O[g][s][i] * rs);
            *(bf16x4*)&O_flat[row * 1024 + h * 64 + 16 * s + 4 * q] = ov;
        }
    }
}

// ---------------- launch ----------------
extern "C" void kernel_launch(void* const* d_in, const int* in_sizes, int n_in,
                              void* d_out, int out_size, void* d_ws, size_t ws_size,
                              hipStream_t stream) {
    const float* query  = (const float*)d_in[0];
    const float* relpos = (const float*)d_in[1];
    const float* w_in   = (const float*)d_in[2];
    const float* b_in   = (const float*)d_in[3];
    const float* w_out  = (const float*)d_in[4];
    const float* b_out  = (const float*)d_in[5];
    float* out = (float*)d_out;

    char* ws = (char*)d_ws;
    size_t off = 0;
    auto alloc = [&](size_t bytes) {
        void* p = ws + off;
        off += (bytes + 255) & ~(size_t)255;
        return p;
    };
    __bf16* qA    = (__bf16*)alloc((size_t)M1 * EE * 2);        // query bf16
    __bf16* winb  = (__bf16*)alloc((size_t)3 * EE * EE * 2);    // in_proj_weight bf16
    __bf16* woutb = (__bf16*)alloc((size_t)EE * EE * 2);        // out_proj_weight bf16
    __bf16* erfp  = (__bf16*)alloc((size_t)SL * DD * 2);        // flipped er bf16
    __bf16* q_ws  = (__bf16*)alloc((size_t)BHC * SL * DD * 2);
    __bf16* k_ws  = (__bf16*)alloc((size_t)BHC * SL * DD * 2);
    __bf16* vT_ws = (__bf16*)alloc((size_t)BHC * SL * DD * 2);
    __bf16* O_flat= (__bf16*)alloc((size_t)M1 * EE * 2);

    // fused conversions + er flip (one launch)
    prep_k<<<8256, 256, 0, stream>>>(query, w_in, w_out, relpos,
                                     qA, winb, woutb, erfp);

    // qkv projection: M=4096, N=3072, K=1024 (v written directly transposed)
    gemm_qkv<<<(3072 / BNt) * (M1 / BMt), 256, 0, stream>>>(
        qA, winb, b_in, q_ws, k_ws, vT_ws);

    attn_kernel<<<512, 256, 0, stream>>>(q_ws, k_ws, vT_ws, erfp, O_flat);

    // out projection: M=4096, N=1024, K=1024; 128x64 tiles -> 512 blocks
    gemm_out<<<512, 256, 0, stream>>>(O_flat, woutb, b_out, out);
}